// Round 4
// baseline (263.292 us; speedup 1.0000x reference)
//
#include <hip/hip_runtime.h>
#include <float.h>
#include <stdint.h>

#define TPB_H 1024              // histogram kernel block
#define TPB_S 512               // sampler kernel block (8 waves: barrier-heavy phases)
#define NB 2048
#define NS 4                    // row-parts for the histogram kernel (4*128 = 512 blocks)
#define CAND_CAP 2048
#define KEPT_CAP 4096
#define MAXLEV 6
#define NW_H (TPB_H / 64)
#define NW_S (TPB_S / 64)
#define FLO (-16.0f)
#define FSC ((float)NB / 32.0f)  // 64 bins per unit over [-16,16)

// Monotone, clamped linear binning — must be bit-identical across all passes.
__device__ __forceinline__ int bin_of(float x, float lo, float sc) {
  float bf = (x - lo) * sc;
  if (!(bf > 0.0f)) return 0;                 // also catches NaN
  if (bf >= (float)(NB - 1)) return NB - 1;
  return (int)bf;
}

__device__ __forceinline__ double wsum_d(double v) {
#pragma unroll
  for (int o = 32; o > 0; o >>= 1) v += __shfl_xor(v, o);
  return v;
}
__device__ __forceinline__ int wsum_i(int v) {
#pragma unroll
  for (int o = 32; o > 0; o >>= 1) v += __shfl_xor(v, o);
  return v;
}
__device__ __forceinline__ float wmax_f(float v) {
#pragma unroll
  for (int o = 32; o > 0; o >>= 1) v = fmaxf(v, __shfl_xor(v, o));
  return v;
}

// ---- sampler-block (TPB_S) reductions/scans ----
__device__ __forceinline__ double blk_sum_d(double v, double* sred, double* out) {
  v = wsum_d(v);
  __syncthreads();
  if ((threadIdx.x & 63) == 0) sred[threadIdx.x >> 6] = v;
  __syncthreads();
  if (threadIdx.x == 0) {
    double t = 0.0;
#pragma unroll
    for (int i = 0; i < NW_S; i++) t += sred[i];
    *out = t;
  }
  __syncthreads();
  return *out;
}

__device__ __forceinline__ int blk_sum_i(int v, int* sredi, int* out) {
  v = wsum_i(v);
  __syncthreads();
  if ((threadIdx.x & 63) == 0) sredi[threadIdx.x >> 6] = v;
  __syncthreads();
  if (threadIdx.x == 0) {
    int t = 0;
#pragma unroll
    for (int i = 0; i < NW_S; i++) t += sredi[i];
    *out = t;
  }
  __syncthreads();
  return *out;
}

// exclusive f64 block prefix: wave shuffle-scan + 8-entry aggregate scan (3 barriers)
__device__ __forceinline__ double blk_exscan_d(double v, double* sw, double* sw2) {
  const int tid = threadIdx.x;
  const int lane = tid & 63, wid = tid >> 6;
  __syncthreads();          // protect sw/sw2 reuse against preceding readers
  double incl = v;
#pragma unroll
  for (int o = 1; o < 64; o <<= 1) {
    double t = __shfl_up(incl, o);
    if (lane >= o) incl += t;
  }
  if (lane == 63) sw[wid] = incl;
  __syncthreads();
  if (tid == 0) {
    double acc = 0.0;
#pragma unroll
    for (int i = 0; i < NW_S; i++) { double t = sw[i]; sw2[i] = acc; acc += t; }
  }
  __syncthreads();
  return sw2[wid] + (incl - v);
}

// Iterate a row; lv = raw logit, gi = global index. V4 is the vec4-covered prefix.
#define ROW_LOOP(...)                                                                  \
  do {                                                                                 \
    for (int i0_ = tid * 4; i0_ < V4; i0_ += TPB_S * 4) {                              \
      const float4 v4_ = *reinterpret_cast<const float4*>(lr + i0_);                   \
      { const float lv = v4_.x; const int gi = i0_ + 0; (void)gi; __VA_ARGS__ }        \
      { const float lv = v4_.y; const int gi = i0_ + 1; (void)gi; __VA_ARGS__ }        \
      { const float lv = v4_.z; const int gi = i0_ + 2; (void)gi; __VA_ARGS__ }        \
      { const float lv = v4_.w; const int gi = i0_ + 3; (void)gi; __VA_ARGS__ }        \
    }                                                                                  \
    for (int gi = V4 + tid; gi < V; gi += TPB_S) {                                     \
      const float lv = lr[gi]; (void)gi; __VA_ARGS__                                   \
    }                                                                                  \
  } while (0)

// ---------------- kernel 1: per (row, part) fixed-bin histogram + partial max ----
extern "C" __global__ void __launch_bounds__(TPB_H) hist_max_kernel(
    const float* __restrict__ logits, int V,
    int* __restrict__ ws_hist, float* __restrict__ ws_max) {
  __shared__ int hist[NB];
  __shared__ float sredf[NW_H];
  const int tid = threadIdx.x;
  const int row = blockIdx.x / NS;
  const int part = blockIdx.x % NS;
  const float* lr = logits + (size_t)row * (size_t)V;
  const int start = (int)(((long long)V * part) / NS);
  const int end = (int)(((long long)V * (part + 1)) / NS);
  const int cnt = end - start;

  for (int i = tid; i < NB; i += TPB_H) hist[i] = 0;
  __syncthreads();

  float mx = -FLT_MAX;
  const int c4 = ((start & 3) == 0) ? (cnt & ~3) : 0;
  for (int i0 = tid * 4; i0 < c4; i0 += TPB_H * 4) {
    const float4 v4 = *reinterpret_cast<const float4*>(lr + start + i0);
    mx = fmaxf(mx, v4.x); atomicAdd(&hist[bin_of(v4.x, FLO, FSC)], 1);
    mx = fmaxf(mx, v4.y); atomicAdd(&hist[bin_of(v4.y, FLO, FSC)], 1);
    mx = fmaxf(mx, v4.z); atomicAdd(&hist[bin_of(v4.z, FLO, FSC)], 1);
    mx = fmaxf(mx, v4.w); atomicAdd(&hist[bin_of(v4.w, FLO, FSC)], 1);
  }
  for (int i = c4 + tid; i < cnt; i += TPB_H) {
    const float lv = lr[start + i];
    mx = fmaxf(mx, lv); atomicAdd(&hist[bin_of(lv, FLO, FSC)], 1);
  }

  mx = wmax_f(mx);
  __syncthreads();
  if ((tid & 63) == 0) sredf[tid >> 6] = mx;
  __syncthreads();
  if (tid == 0) {
    float t = sredf[0];
    for (int i = 1; i < NW_H; i++) t = fmaxf(t, sredf[i]);
    ws_max[blockIdx.x] = t;
  }
  __syncthreads();
  int* dst = ws_hist + (size_t)blockIdx.x * NB;
  for (int i = tid; i < NB; i += TPB_H) dst[i] = hist[i];
}

// ---------------- kernel 2: per-row select + gather + sort + sample ---------------
extern "C" __global__ void __launch_bounds__(TPB_S) sampler_kernel(
    const float* __restrict__ logits, const float* __restrict__ temps,
    const void* __restrict__ topks_raw, const float* __restrict__ topps,
    const float* __restrict__ minps, const float* __restrict__ uarr,
    int* __restrict__ out, const int* __restrict__ ws_hist,
    const float* __restrict__ ws_max, int haveWs, int V, int B) {
  const int row = blockIdx.x;
  const int tid = threadIdx.x;

  __shared__ float cand[CAND_CAP];
  __shared__ int hist[NB];          // dead after locate; stays live for fallback only
  __shared__ int cand_idx[CAND_CAP];
  __shared__ int kept_idx[KEPT_CAP];
  __shared__ float kept_val[KEPT_CAP];
  __shared__ double sred[NW_S], sred2[NW_S];
  __shared__ int sredi[NW_S];
  __shared__ float sredf[NW_S];
  __shared__ double s_outd;
  __shared__ int s_outi;
  __shared__ float lev_lo[MAXLEV], lev_sc[MAXLEV];
  __shared__ int lev_bin[MAXLEV];
  __shared__ int s_nlev, s_bin, s_kk, s_cntbin, s_cnt, s_ccnt, s_pos;
  __shared__ float s_lmax, s_vkl, s_lo, s_sc;

  const float* lr = logits + (size_t)row * (size_t)V;
  const float T = temps[row];
  const float topp = topps[row];
  const float minp = minps[row];
  const float u = uarr[row];

  // top_ks: reference dtype is int64 but the harness may hand us int32.
  // Detect via element-0 high word (k >= 1 always, so int32 layout has ip[1] != 0).
  long long kraw;
  {
    const int* ip = (const int*)topks_raw;
    const bool is64 = (B < 2) || (ip[1] == 0);
    kraw = is64 ? ((const long long*)topks_raw)[row] : (long long)ip[row];
  }
  long long kidx = kraw - 1;
  if (kidx < 0) kidx = 0;
  if (kidx > (long long)(V - 1)) kidx = (long long)(V - 1);
  const int k = (int)kidx + 1;

  const int V4 = ((V & 3) == 0) ? V : 0;

  // ---------- stage A: row max + fixed-bound histogram ----------
  if (haveWs) {
    for (int i = tid; i < NB; i += TPB_S) {
      int t = 0;
#pragma unroll
      for (int p = 0; p < NS; p++) t += ws_hist[(size_t)(row * NS + p) * NB + i];
      hist[i] = t;
    }
    if (tid == 0) {
      float m = ws_max[row * NS];
#pragma unroll
      for (int p = 1; p < NS; p++) m = fmaxf(m, ws_max[row * NS + p]);
      s_lmax = m;
    }
    __syncthreads();
  } else {
    for (int i = tid; i < NB; i += TPB_S) hist[i] = 0;
    __syncthreads();
    float mx = -FLT_MAX;
    ROW_LOOP(mx = fmaxf(mx, lv); atomicAdd(&hist[bin_of(lv, FLO, FSC)], 1););
    mx = wmax_f(mx);
    __syncthreads();
    if ((tid & 63) == 0) sredf[tid >> 6] = mx;
    __syncthreads();
    if (tid == 0) {
      float t = sredf[0];
      for (int i = 1; i < NW_S; i++) t = fmaxf(t, sredf[i]);
      s_lmax = t;
    }
    __syncthreads();
  }
  const float lmax = s_lmax;

  // ---------- stage B: locate bin of the k-th largest (refinement = fallback) ----
  if (tid == 0) {
    s_kk = k; s_nlev = 0; s_vkl = lmax; s_lo = FLO; s_sc = FSC;
  }
  __syncthreads();

  for (int lev = 0; lev < MAXLEV; lev++) {
    if (tid < 64) {   // wave 0: find bin holding the s_kk-th largest from the top
      const int l = tid;
      const int b0 = NB - (l + 1) * (NB / 64);   // lane 0 covers highest bins
      int c = 0;
#pragma unroll
      for (int j = 0; j < NB / 64; j++) c += hist[b0 + j];
      int incl = c;
#pragma unroll
      for (int o = 1; o < 64; o <<= 1) {
        int t2 = __shfl_up(incl, o);
        if (l >= o) incl += t2;
      }
      const int pref = incl - c;  // count in strictly-higher chunks
      const int kk = s_kk;
      if (pref < kk && kk <= pref + c) {
        int rem = kk - pref;
        for (int j = NB / 64 - 1; j >= 0; j--) {
          const int h = hist[b0 + j];
          if (rem <= h) { s_bin = b0 + j; s_cntbin = h; s_kk = rem; break; }
          rem -= h;
        }
      }
    }
    __syncthreads();
    if (tid == 0) {
      lev_lo[lev] = s_lo; lev_sc[lev] = s_sc; lev_bin[lev] = s_bin;
      s_nlev = lev + 1;
    }
    __syncthreads();
    if (s_cntbin <= CAND_CAP) break;
    // fallback refinement (extra full-row pass; not expected on benchmark data)
    const float nlo = s_lo + (float)s_bin / s_sc;
    const float nsc = s_sc * (float)NB;
    const bool degw = !((nlo + (float)NB / nsc) > nlo);
    if (lev + 1 >= MAXLEV || degw) break;
    __syncthreads();
    if (tid == 0) { s_lo = nlo; s_sc = nsc; }
    for (int i = tid; i < NB; i += TPB_S) hist[i] = 0;
    __syncthreads();
    const int nl = lev + 1;
    ROW_LOOP(
      bool memb = true;
      for (int L = 0; L < nl; L++) {
        if (bin_of(lv, lev_lo[L], lev_sc[L]) != lev_bin[L]) { memb = false; break; }
      }
      if (memb) atomicAdd(&hist[bin_of(lv, nlo, nsc)], 1););
    __syncthreads();
  }

  // ---------- stage C: fused gather (kept-direct + candidates w/ indices) --------
  if (tid == 0) { s_cnt = 0; s_ccnt = 0; }
  __syncthreads();
  {
    const int nl = s_nlev;
    ROW_LOOP(
      int cls = 2;          // 2 = full-chain member (candidate)
      for (int L = 0; L < nl; L++) {
        const int b = bin_of(lv, lev_lo[L], lev_sc[L]);
        if (b > lev_bin[L]) { cls = 1; break; }   // strictly above chain => > v_k
        if (b < lev_bin[L]) { cls = 0; break; }   // below => < v_k
      }
      if (cls == 1) {
        int p = atomicAdd(&s_cnt, 1);
        if (p < KEPT_CAP) { kept_idx[p] = gi; kept_val[p] = lv; }
      } else if (cls == 2) {
        int p = atomicAdd(&s_ccnt, 1);
        if (p < CAND_CAP) { cand[p] = lv; cand_idx[p] = gi; }
      });
  }
  __syncthreads();

  // ---------- stage D: exact tie-aware rank select of v_k among candidates -------
  {
    const int n = (s_ccnt < CAND_CAP) ? s_ccnt : CAND_CAP;
    int kkq = s_kk;
    if (kkq > n) kkq = n;
    for (int t = tid; t < n; t += TPB_S) {
      const float v = cand[t];
      int rank = 0;
      for (int j = 0; j < n; j++) {
        const float cj = cand[j];
        rank += (cj > v) ? 1 : ((cj == v && j < t) ? 1 : 0);
      }
      if (rank == kkq - 1) s_vkl = v;   // exactly one thread matches
    }
  }
  __syncthreads();
  const float vkl = s_vkl;

  // append candidates >= v_k to the kept set (from LDS, no global pass)
  {
    const int n = (s_ccnt < CAND_CAP) ? s_ccnt : CAND_CAP;
    for (int t = tid; t < n; t += TPB_S) {
      const float v = cand[t];
      if (v >= vkl) {
        int p = atomicAdd(&s_cnt, 1);
        if (p < KEPT_CAP) { kept_idx[p] = cand_idx[t]; kept_val[p] = v; }
      }
    }
  }
  __syncthreads();
  const int n1 = (s_cnt < KEPT_CAP) ? s_cnt : KEPT_CAP;
  if (n1 <= 0) {  // unreachable with valid data
    if (tid == 0) out[row] = 0;
    return;
  }

  // ---------- logits -> probs (precise exp only for kept) ----------
  const float xmaxT = lmax / T;  // == max_i fl(l_i/T) (division by T>0 is monotone)
  double lsum = 0.0;
  for (int t = tid; t < n1; t += TPB_S) {
    const float x = kept_val[t] / T;
    const float w = expf(x - xmaxT);
    kept_val[t] = w;
    lsum += (double)w;
  }
  const float s1f = (float)blk_sum_d(lsum, sred, &s_outd);
  for (int t = tid; t < n1; t += TPB_S) kept_val[t] = kept_val[t] / s1f;

  // pad & bitonic sort descending by value (idx carried)
  int M = 1;
  while (M < n1) M <<= 1;
  if (M < 2) M = 2;
  __syncthreads();
  for (int t = n1 + tid; t < M; t += TPB_S) { kept_val[t] = -1.0f; kept_idx[t] = 0x7FFFFFFF; }
  __syncthreads();
  for (int len = 2; len <= M; len <<= 1) {
    for (int str = len >> 1; str > 0; str >>= 1) {
      for (int t = tid; t < (M >> 1); t += TPB_S) {
        const int i = ((t & ~(str - 1)) << 1) | (t & (str - 1));
        const int j2 = i | str;
        const float vi = kept_val[i], vj = kept_val[j2];
        const bool descSeg = ((i & len) == 0);
        if (descSeg ? (vi < vj) : (vi > vj)) {
          kept_val[i] = vj; kept_val[j2] = vi;
          const int ti = kept_idx[i];
          kept_idx[i] = kept_idx[j2]; kept_idx[j2] = ti;
        }
      }
      __syncthreads();
    }
  }

  // ---------- top-p: (excl cum < p) keeps a prefix; then >= p_thresh ----------
  const int C = (M + TPB_S - 1) / TPB_S;
  double cls0 = 0.0;
  for (int j = 0; j < C; j++) {
    const int p = tid * C + j;
    if (p < n1) cls0 += (double)kept_val[p];
  }
  const double excl0 = blk_exscan_d(cls0, sred, sred2);
  int lc = 0;
  {
    double run = excl0;
    for (int j = 0; j < C; j++) {
      const int p = tid * C + j;
      if (p < n1) {
        if (run < (double)topp) lc++;
        run += (double)kept_val[p];
      }
    }
  }
  const int cnt = blk_sum_i(lc, sredi, &s_outi);  // >= 1 always
  const float pthr = kept_val[cnt - 1];

  int ln2 = 0;
  double ls2 = 0.0;
  for (int j = 0; j < C; j++) {
    const int p = tid * C + j;
    if (p < n1) {
      const float v = kept_val[p];
      if (v >= pthr) { ln2++; ls2 += (double)v; }
    }
  }
  const int n2 = blk_sum_i(ln2, sredi, &s_outi);
  const float s2f = (float)blk_sum_d(ls2, sred, &s_outd);

  // ---------- min-p (survivors are a prefix in sorted order) ----------
  const float maxr = kept_val[0] / s2f;
  const float th4 = minp * maxr;
  int ln3 = 0;
  double ls3 = 0.0;
  for (int j = 0; j < C; j++) {
    const int p = tid * C + j;
    if (p < n2) {
      const float r = kept_val[p] / s2f;
      if (r >= th4) { ln3++; ls3 += (double)r; }
    }
  }
  const int n3 = blk_sum_i(ln3, sredi, &s_outi);
  const float s3f = (float)blk_sum_d(ls3, sred, &s_outd);

  // ---------- finalize probs, sort survivors by index, inverse-CDF ----------
  int M3 = 1;
  while (M3 < n3) M3 <<= 1;
  if (M3 < 2) M3 = 2;
  __syncthreads();
  for (int t = tid; t < M3; t += TPB_S) {
    if (t < n3) {
      const float r = kept_val[t] / s2f;
      kept_val[t] = r / s3f;
    } else {
      kept_val[t] = 0.0f;
      kept_idx[t] = 0x7FFFFFFF;
    }
  }
  __syncthreads();
  for (int len = 2; len <= M3; len <<= 1) {
    for (int str = len >> 1; str > 0; str >>= 1) {
      for (int t = tid; t < (M3 >> 1); t += TPB_S) {
        const int i = ((t & ~(str - 1)) << 1) | (t & (str - 1));
        const int j2 = i | str;
        const int ki = kept_idx[i], kj = kept_idx[j2];
        const bool ascSeg = ((i & len) == 0);
        if (ascSeg ? (ki > kj) : (ki < kj)) {
          kept_idx[i] = kj; kept_idx[j2] = ki;
          const float tv = kept_val[i];
          kept_val[i] = kept_val[j2]; kept_val[j2] = tv;
        }
      }
      __syncthreads();
    }
  }
  const int C3 = (M3 + TPB_S - 1) / TPB_S;
  double cls3 = 0.0;
  for (int j = 0; j < C3; j++) {
    const int p = tid * C3 + j;
    if (p < n3) cls3 += (double)kept_val[p];
  }
  const double e5 = blk_exscan_d(cls3, sred, sred2);
  if (tid == 0) s_pos = 0x7FFFFFFF;
  __syncthreads();
  {
    double run = e5;
    int found = -1;
    for (int j = 0; j < C3; j++) {
      const int p = tid * C3 + j;
      if (p < n3) {
        run += (double)kept_val[p];
        if (run >= (double)u) { found = p; break; }
      }
    }
    if (found >= 0) atomicMin(&s_pos, found);
  }
  __syncthreads();
  if (tid == 0) {
    int token;
    if (!(u > 0.0f)) token = 0;                   // all cdf >= 0 == u -> count 0
    else if (s_pos == 0x7FFFFFFF) token = V - 1;  // u beyond total mass -> clip
    else token = kept_idx[s_pos];                 // == count of cdf entries < u
    out[row] = token;
  }
}

extern "C" void kernel_launch(void* const* d_in, const int* in_sizes, int n_in,
                              void* d_out, int out_size, void* d_ws, size_t ws_size,
                              hipStream_t stream) {
  const float* logits = (const float*)d_in[0];
  const float* temps = (const float*)d_in[1];
  const void* topks = d_in[2];
  const float* topps = (const float*)d_in[3];
  const float* minps = (const float*)d_in[4];
  const float* u = (const float*)d_in[5];
  int* out = (int*)d_out;
  const int B = in_sizes[1];
  const int V = in_sizes[0] / B;
  (void)n_in; (void)out_size;

  const size_t needHist = (size_t)NS * (size_t)B * (size_t)NB * sizeof(int);
  const size_t need = needHist + (size_t)NS * (size_t)B * sizeof(float);
  const int haveWs = (d_ws != nullptr && ws_size >= need) ? 1 : 0;
  int* ws_hist = (int*)d_ws;
  float* ws_max = (float*)((char*)d_ws + needHist);

  if (haveWs) {
    hist_max_kernel<<<dim3(B * NS), dim3(TPB_H), 0, stream>>>(logits, V, ws_hist, ws_max);
  }
  sampler_kernel<<<dim3(B), dim3(TPB_S), 0, stream>>>(logits, temps, topks, topps,
                                                      minps, u, out, ws_hist, ws_max,
                                                      haveWs, V, B);
}